// Round 5
// baseline (266.729 us; speedup 1.0000x reference)
//
#include <hip/hip_runtime.h>
#include <stdint.h>

#pragma clang fp contract(off)

#define BB 32
#define NN 200000
#define N4 50000
#define KK 500
#define KEEPN 100
#define CAND_CAP 4096
#define CONF 0.05f
#define NMSTHR 0.5f
#define HSHIFT 18          // top-14-bit score prefix
#define HBINS 16384
#define SELTARGET 576      // radix-narrow until <= this many candidates

typedef unsigned long long u64;

__device__ __forceinline__ unsigned int ordkey(float s) {
    unsigned int u = __float_as_uint(s);
    return (u & 0x80000000u) ? ~u : (u | 0x80000000u);
}

// One block per batch. All phases in one kernel; LDS regions are phase-disjoint
// unions inside one 64 KB block (64 KB static LDS proven on gfx950).
__global__ __launch_bounds__(1024) void fused_kernel(const float4* __restrict__ ps4,
                                                     const float* __restrict__ pboxes,
                                                     const int* __restrict__ plabels,
                                                     float* __restrict__ out) {
    __shared__ __align__(16) char smem[65536];
    // ---- region map (liveness is strictly phase-ordered; barriers separate) ----
    unsigned int* hist = (unsigned int*)smem;            // [0,65536)  phase A only
    u64*   kbuf   = (u64*)smem;                          // [0,32768)  B: keys -> E: mask rows
    u64*   sel    = (u64*)(smem + 32768);                // [32768,40960) D..E
    float* sboxes = (float*)(smem + 40960);              // 500*4 f32   E
    float* sscore = (float*)(smem + 48960);              // 500 f32     E
    int*   slabel = (int*)(smem + 50960);                // 500 i32     E
    int*   clist  = (int*)(smem + 52960);                // 500 i32     E
    unsigned int* h = (unsigned int*)(smem + 54960);     // 256 u32     C
    int* ccnt  = (int*)(smem + 55984);                   // 21
    int* coff  = (int*)(smem + 56068);                   // 22
    int* cfill = (int*)(smem + 56160);                   // 21
    u64* validw = (u64*)(smem + 56248);                  // 8 (8-aligned)
    int* kept   = (int*)(smem + 56312);                  // 100
    float* wred = (float*)(smem + 56712);                // 16
    unsigned int* wsum = (unsigned int*)(smem + 57344);  // 16, A2 (post-hist-read)
    u64* s_prefix = (u64*)(smem + 57472);
    unsigned int* s_p14    = (unsigned int*)(smem + 57480);
    int*          s_lcnt   = (int*)(smem + 57484);
    int*          s_sc     = (int*)(smem + 57488);
    unsigned int* s_region = (unsigned int*)(smem + 57492);
    unsigned int* s_cntgt  = (unsigned int*)(smem + 57496);
    int*          s_nk     = (int*)(smem + 57500);
    float*        s_maxc   = (float*)(smem + 57504);

    const int b = blockIdx.x;
    const int tid = threadIdx.x;
    const int lane = tid & 63;
    const int wv = tid >> 6;

    const float4* p = ps4 + (size_t)b * N4;

    // ================= Phase A: 14-bit LDS histogram =================
    for (int i = tid; i < HBINS; i += 1024) hist[i] = 0;
    __syncthreads();
    for (int i = tid; i < N4; i += 1024) {
        float4 v = p[i];
        atomicAdd(&hist[ordkey(v.x) >> HSHIFT], 1u);
        atomicAdd(&hist[ordkey(v.y) >> HSHIFT], 1u);
        atomicAdd(&hist[ordkey(v.z) >> HSHIFT], 1u);
        atomicAdd(&hist[ordkey(v.w) >> HSHIFT], 1u);
    }
    __syncthreads();

    // ================= Phase A2: threshold prefix (wave suffix-scans) ========
    unsigned int v16[16];
    unsigned int tot = 0;
    for (int j = 0; j < 16; ++j) { v16[j] = hist[tid * 16 + j]; tot += v16[j]; }
    __syncthreads();   // all hist reads done; hist region dead from here on
    unsigned int sfx = tot;                       // suffix-incl within wave
    for (int off = 1; off < 64; off <<= 1) {
        unsigned int t2 = __shfl_down(sfx, off);
        sfx += (lane + off < 64) ? t2 : 0u;
    }
    if (lane == 0) wsum[wv] = sfx;                // wave total
    __syncthreads();
    unsigned int wafter = 0;
    for (int w2 = wv + 1; w2 < 16; ++w2) wafter += wsum[w2];
    unsigned int after_me = wafter + (sfx - tot); // bins after my 16
    unsigned int sn = after_me;
    for (int j = 15; j >= 0; --j) {
        unsigned int s = sn + v16[j];
        if (s >= (unsigned)KK && sn < (unsigned)KK) *s_p14 = (unsigned)(tid * 16 + j);
        sn = s;
    }
    if (tid == 0) *s_lcnt = 0;
    __syncthreads();

    // ================= Phase B: compact candidates into LDS ==================
    const unsigned int p14 = *s_p14;
    for (int i = tid; i < N4; i += 1024) {
        float4 v = p[i];
        int n = i << 2;
        unsigned int u;
        u = ordkey(v.x);
        if ((u >> HSHIFT) >= p14) { int pos = atomicAdd(s_lcnt, 1);
            if (pos < CAND_CAP) kbuf[pos] = ((u64)u << 32) | (unsigned int)(~(unsigned int)(n)); }
        u = ordkey(v.y);
        if ((u >> HSHIFT) >= p14) { int pos = atomicAdd(s_lcnt, 1);
            if (pos < CAND_CAP) kbuf[pos] = ((u64)u << 32) | (unsigned int)(~(unsigned int)(n + 1)); }
        u = ordkey(v.z);
        if ((u >> HSHIFT) >= p14) { int pos = atomicAdd(s_lcnt, 1);
            if (pos < CAND_CAP) kbuf[pos] = ((u64)u << 32) | (unsigned int)(~(unsigned int)(n + 2)); }
        u = ordkey(v.w);
        if ((u >> HSHIFT) >= p14) { int pos = atomicAdd(s_lcnt, 1);
            if (pos < CAND_CAP) kbuf[pos] = ((u64)u << 32) | (unsigned int)(~(unsigned int)(n + 3)); }
    }
    __syncthreads();
    int m = *s_lcnt;
    if (m > CAND_CAP) m = CAND_CAP;

    // ================= Phase C: radix-narrow to <= SELTARGET =================
    u64 thr; int seln;
    int shift = 56;
    if (m <= SELTARGET) {
        thr = 0ULL; seln = m;
    } else {
        if (tid == 0) { *s_prefix = 0ULL; *s_cntgt = 0u; }
        __syncthreads();
        for (; shift >= 0; shift -= 8) {
            if (tid < 256) h[tid] = 0u;
            __syncthreads();
            u64 pref = *s_prefix;
            unsigned int cg = *s_cntgt;
            for (int i = tid; i < m; i += 1024) {
                u64 k = kbuf[i];
                bool match = (shift == 56) || ((k >> (shift + 8)) == pref);
                if (match) atomicAdd(&h[(unsigned int)((k >> shift) & 0xFF)], 1u);
            }
            __syncthreads();
            if (wv == 0) {                         // 256-bin suffix-select in one wave
                unsigned int b4[4]; unsigned int lt = 0;
                for (int j = 0; j < 4; ++j) { b4[j] = h[lane * 4 + j]; lt += b4[j]; }
                unsigned int sx = lt;
                for (int off = 1; off < 64; off <<= 1) {
                    unsigned int t2 = __shfl_down(sx, off);
                    sx += (lane + off < 64) ? t2 : 0u;
                }
                unsigned int after = sx - lt;
                unsigned int target = (unsigned)KK - cg;
                unsigned int sn2 = after;
                for (int j = 3; j >= 0; --j) {
                    unsigned int s = sn2 + b4[j];
                    if (s >= target && sn2 < target) {
                        unsigned int bin = (unsigned)(lane * 4 + j);
                        *s_region = b4[j];
                        *s_cntgt = cg + sn2;
                        *s_prefix = (shift == 56) ? (u64)bin : ((pref << 8) | (u64)bin);
                    }
                    sn2 = s;
                }
            }
            __syncthreads();
            if (*s_cntgt + *s_region <= (unsigned)SELTARGET) break;
        }
        if (shift < 0) shift = 0;
        thr = (*s_prefix) << shift;
        seln = (int)(*s_cntgt + *s_region);
    }

    // ================= Phase D: gather >= thr, rank, scatter sorted ==========
    if (tid == 0) *s_sc = 0;
    __syncthreads();
    for (int r0 = 0; r0 < 4; ++r0) {
        int i = tid + r0 * 1024;
        u64 k = (i < m) ? kbuf[i] : 0ULL;
        bool pq = (i < m) && (k >= thr);
        u64 mb = __ballot(pq);
        int pre = __popcll(mb & ((1ULL << lane) - 1ULL));
        int tt = __popcll(mb);
        int base = 0;
        if (lane == 0 && tt > 0) base = atomicAdd(s_sc, tt);
        base = __shfl(base, 0);
        if (pq) sel[base + pre] = k;
    }
    __syncthreads();

    u64 myk = (tid < seln) ? sel[tid] : 0ULL;
    int r = 0;
    if ((tid & ~63) < seln) {                      // wave-uniform activity guard
        for (int base = 0; base < seln; base += 64) {
            int i2 = base + lane;
            u64 other = (i2 < seln) ? sel[i2] : 0ULL;
            unsigned int olo = (unsigned int)other, ohi = (unsigned int)(other >> 32);
            int lim = seln - base; if (lim > 64) lim = 64;
            for (int t2 = 0; t2 < lim; ++t2) {     // VALU-pipe broadcast compares
                unsigned int blo = (unsigned int)__builtin_amdgcn_readlane((int)olo, t2);
                unsigned int bhi = (unsigned int)__builtin_amdgcn_readlane((int)ohi, t2);
                u64 o = ((u64)bhi << 32) | (u64)blo;
                r += (o > myk) ? 1 : 0;
            }
        }
    }
    __syncthreads();
    if (tid < seln && r < KK) sel[r] = myk;        // keys unique -> ranks unique
    __syncthreads();

    // ================= Phase E: extract, NMS, outputs ========================
    float sc = -1.0f;
    if (tid < KK) {
        u64 key = sel[tid];
        unsigned int lo = (unsigned int)key;
        unsigned int hi = (unsigned int)(key >> 32);
        int idx = (int)(~lo);
        unsigned int bits = (hi & 0x80000000u) ? (hi & 0x7FFFFFFFu) : ~hi;
        sc = __uint_as_float(bits);
        sscore[tid] = sc;
        const float4 bx = *(const float4*)(pboxes + (((size_t)b * NN + (size_t)idx) << 2));
        sboxes[tid * 4 + 0] = bx.x; sboxes[tid * 4 + 1] = bx.y;
        sboxes[tid * 4 + 2] = bx.z; sboxes[tid * 4 + 3] = bx.w;
        slabel[tid] = plabels[(size_t)b * NN + idx];
    }
    __syncthreads();

    bool vq = (tid < KK) && (sc > CONF);
    u64 bm = __ballot(vq);
    if (lane == 0 && wv < 8) validw[wv] = bm;
    float lm = vq ? fmaxf(fmaxf(sboxes[tid * 4 + 0], sboxes[tid * 4 + 1]),
                          fmaxf(sboxes[tid * 4 + 2], sboxes[tid * 4 + 3])) : 0.0f;
    for (int off = 32; off > 0; off >>= 1) lm = fmaxf(lm, __shfl_down(lm, off));
    if (lane == 0) wred[wv] = lm;
    __syncthreads();
    if (tid < 64) {
        float x = (tid < 16) ? wred[tid] : 0.0f;
        for (int off = 8; off > 0; off >>= 1) x = fmaxf(x, __shfl_down(x, off));
        if (tid == 0) *s_maxc = x;
    }
    if (tid < 21) { ccnt[tid] = 0; cfill[tid] = 0; }
    __syncthreads();
    if (tid < KK) atomicAdd(&ccnt[slabel[tid]], 1);
    __syncthreads();
    if (tid == 0) {
        int acc = 0;
        for (int c = 0; c < 21; ++c) { coff[c] = acc; acc += ccnt[c]; }
        coff[21] = acc;
    }
    __syncthreads();
    if (tid < KK) {
        int c = slabel[tid];
        int pos = atomicAdd(&cfill[c], 1);
        clist[coff[c] + pos] = tid;
    }
    for (int i = tid; i < KK * 8; i += 1024) kbuf[i] = 0ULL;   // mask rows
    __syncthreads();

    // IoU > thr rows, same-class only (cross-class IoU is exactly 0 after offsets).
    // Same-class offsets are the SAME fp value -> identical arithmetic to reference.
    float ap1 = *s_maxc + 1.0f;
    if (tid < KK) {
        int c = slabel[tid];
        int n = ccnt[c], base0 = coff[c];
        float aoff = (float)c * ap1;
        float a0 = sboxes[tid * 4 + 0] + aoff, a1 = sboxes[tid * 4 + 1] + aoff;
        float a2 = sboxes[tid * 4 + 2] + aoff, a3 = sboxes[tid * 4 + 3] + aoff;
        float areaA = (a2 - a0) * (a3 - a1);
        for (int q = 0; q < n; ++q) {
            int j = clist[base0 + q];
            float b0 = sboxes[j * 4 + 0] + aoff, b1f = sboxes[j * 4 + 1] + aoff;
            float b2f = sboxes[j * 4 + 2] + aoff, b3f = sboxes[j * 4 + 3] + aoff;
            float lt0 = fmaxf(a0, b0), lt1 = fmaxf(a1, b1f);
            float rb0 = fminf(a2, b2f), rb1 = fminf(a3, b3f);
            float ww = fmaxf(rb0 - lt0, 0.0f), hh = fmaxf(rb1 - lt1, 0.0f);
            float inter = ww * hh;
            float areaB = (b2f - b0) * (b3f - b1f);
            float iou = inter / (areaA + areaB - inter);
            if (iou > NMSTHR) kbuf[tid * 8 + (j >> 6)] |= (1ULL << (j & 63));
        }
    }
    __syncthreads();

    if (tid < 64) {                                 // greedy scan, wave 0
        u64 remv = 0ULL;
        u64 vw_reg = (lane < 8) ? validw[lane] : 0ULL;
        int nk = 0;
        for (int i = 0; i < KK && nk < KEEPN; ++i) {
            int w = i >> 6, bpos = i & 63;
            u64 rw = __shfl(remv, w);
            u64 vv = __shfl(vw_reg, w);
            bool alive = (((vv >> bpos) & 1ULL) != 0ULL) && (((rw >> bpos) & 1ULL) == 0ULL);
            if (alive) {
                if (lane == 0) kept[nk] = i;
                u64 roww = (lane < 8) ? kbuf[i * 8 + lane] : 0ULL;
                remv |= roww;
                nk++;
            }
        }
        if (lane == 0) *s_nk = nk;
    }
    __syncthreads();

    if (tid < KEEPN) {
        const int O_BOX = BB * KEEPN;
        const int O_LAB = BB * KEEPN * 5;
        const int O_SCO = BB * KEEPN * 6;
        const int O_VAL = BB * KEEPN * 7;
        bool q = tid < *s_nk;
        int i = q ? kept[tid] : 0;
        int g = b * KEEPN + tid;
        out[g]                 = q ? (float)b : -1.0f;
        out[O_BOX + g * 4 + 0] = q ? sboxes[i * 4 + 0] : 0.0f;
        out[O_BOX + g * 4 + 1] = q ? sboxes[i * 4 + 1] : 0.0f;
        out[O_BOX + g * 4 + 2] = q ? sboxes[i * 4 + 2] : 0.0f;
        out[O_BOX + g * 4 + 3] = q ? sboxes[i * 4 + 3] : 0.0f;
        out[O_LAB + g]         = q ? (float)slabel[i] : -1.0f;
        out[O_SCO + g]         = q ? sscore[i] : 0.0f;
        out[O_VAL + g]         = q ? 1.0f : 0.0f;
    }
}

extern "C" void kernel_launch(void* const* d_in, const int* in_sizes, int n_in,
                              void* d_out, int out_size, void* d_ws, size_t ws_size,
                              hipStream_t stream) {
    const float* pscores = (const float*)d_in[0];
    const float* pboxes  = (const float*)d_in[1];
    const int*   plabels = (const int*)d_in[2];
    float* out = (float*)d_out;
    fused_kernel<<<BB, 1024, 0, stream>>>((const float4*)pscores, pboxes, plabels, out);
}

// Round 6
// 227.014 us; speedup vs baseline: 1.1749x; 1.1749x over previous
//
#include <hip/hip_runtime.h>
#include <stdint.h>

#pragma clang fp contract(off)

#define BB 32
#define NN 200000
#define N4 50000
#define KK 500
#define KEEPN 100
#define CONF 0.05f
#define NMSTHR 0.5f
#define SLICES 8
#define SLICE_F4 6250          // float4 per slice (25000 elems)
#define LBINS 8192
#define LSHIFT 19              // top 13 bits of ordkey
#define LOCAL_CAP 2048
#define OUT_CAP 576
#define M_CAP (SLICES * OUT_CAP)   // 4608

typedef unsigned long long u64;

// ---- workspace layout (bytes) ----
// 0       : cand 32*8*576*8 = 1179648   (slices fully rewritten each call)
// 1179648 : cnts 256*4 = 1024           (fully rewritten each call; no memset)

__device__ __forceinline__ unsigned int ordkey(float s) {
    unsigned int u = __float_as_uint(s);
    return (u & 0x80000000u) ? ~u : (u | 0x80000000u);
}

// ---- stage 1: per-slice local top-500 superset, narrowed to <= 576 keys ----
// 256 blocks (8 slices x 32 batches) keep the score read at full HBM width.
__global__ __launch_bounds__(1024) void select_kernel(const float4* __restrict__ ps4,
                                                      u64* __restrict__ cand,
                                                      unsigned int* __restrict__ cnts) {
    __shared__ unsigned int hist[LBINS];     // 32 KB
    __shared__ u64 keys[LOCAL_CAP];          // 16 KB
    __shared__ unsigned int h[256];
    __shared__ unsigned int wsum[16];
    __shared__ u64 s_prefix;
    __shared__ unsigned int s_t13, s_region, s_cntgt;
    __shared__ int s_lcnt, s_sc;

    const int b = blockIdx.y, x = blockIdx.x;
    const int tid = threadIdx.x, lane = tid & 63, wv = tid >> 6;
    const float4* p = ps4 + (size_t)b * N4 + (size_t)x * SLICE_F4;

    // pass A: 13-bit LDS histogram of this slice
    for (int i = tid; i < LBINS; i += 1024) hist[i] = 0;
    __syncthreads();
    for (int i = tid; i < SLICE_F4; i += 1024) {
        float4 v = p[i];
        atomicAdd(&hist[ordkey(v.x) >> LSHIFT], 1u);
        atomicAdd(&hist[ordkey(v.y) >> LSHIFT], 1u);
        atomicAdd(&hist[ordkey(v.z) >> LSHIFT], 1u);
        atomicAdd(&hist[ordkey(v.w) >> LSHIFT], 1u);
    }
    __syncthreads();

    // local threshold: 13-bit prefix where suffix count crosses KK (wave scans)
    unsigned int v8[8], tot = 0;
    for (int j = 0; j < 8; ++j) { v8[j] = hist[tid * 8 + j]; tot += v8[j]; }
    unsigned int sfx = tot;
    for (int off = 1; off < 64; off <<= 1) {
        unsigned int t2 = __shfl_down(sfx, off);
        sfx += (lane + off < 64) ? t2 : 0u;
    }
    if (lane == 0) wsum[wv] = sfx;
    __syncthreads();
    unsigned int wafter = 0;
    for (int w2 = wv + 1; w2 < 16; ++w2) wafter += wsum[w2];
    unsigned int sn = wafter + (sfx - tot);
    for (int j = 7; j >= 0; --j) {
        unsigned int s = sn + v8[j];
        if (s >= (unsigned)KK && sn < (unsigned)KK) s_t13 = (unsigned)(tid * 8 + j);
        sn = s;
    }
    if (tid == 0) s_lcnt = 0;
    __syncthreads();

    // pass B: compact >= threshold (re-read is L2-hot: 100 KB/block private)
    const unsigned int t13 = s_t13;
    const int ebase = x * (SLICE_F4 * 4);
    for (int i = tid; i < SLICE_F4; i += 1024) {
        float4 v = p[i];
        int n = ebase + (i << 2);
        unsigned int u;
        u = ordkey(v.x); if ((u >> LSHIFT) >= t13) { int pos = atomicAdd(&s_lcnt, 1);
            if (pos < LOCAL_CAP) keys[pos] = ((u64)u << 32) | (unsigned int)(~(unsigned int)(n)); }
        u = ordkey(v.y); if ((u >> LSHIFT) >= t13) { int pos = atomicAdd(&s_lcnt, 1);
            if (pos < LOCAL_CAP) keys[pos] = ((u64)u << 32) | (unsigned int)(~(unsigned int)(n + 1)); }
        u = ordkey(v.z); if ((u >> LSHIFT) >= t13) { int pos = atomicAdd(&s_lcnt, 1);
            if (pos < LOCAL_CAP) keys[pos] = ((u64)u << 32) | (unsigned int)(~(unsigned int)(n + 2)); }
        u = ordkey(v.w); if ((u >> LSHIFT) >= t13) { int pos = atomicAdd(&s_lcnt, 1);
            if (pos < LOCAL_CAP) keys[pos] = ((u64)u << 32) | (unsigned int)(~(unsigned int)(n + 3)); }
    }
    __syncthreads();
    int m = s_lcnt; if (m > LOCAL_CAP) m = LOCAL_CAP;

    // radix-narrow to <= OUT_CAP keys (still a top-500 superset: cntgt < 500)
    u64 thr; int seln;
    if (m <= OUT_CAP) {
        thr = 0ULL; seln = m;
    } else {
        if (tid == 0) { s_prefix = 0ULL; s_cntgt = 0u; }
        __syncthreads();
        int shift = 56;
        for (; shift >= 0; shift -= 8) {
            if (tid < 256) h[tid] = 0u;
            __syncthreads();
            u64 pref = s_prefix;
            unsigned int cg = s_cntgt;
            for (int i = tid; i < m; i += 1024) {
                u64 k = keys[i];
                bool match = (shift == 56) || ((k >> (shift + 8)) == pref);
                if (match) atomicAdd(&h[(unsigned int)((k >> shift) & 0xFF)], 1u);
            }
            __syncthreads();
            if (wv == 0) {
                unsigned int b4[4]; unsigned int lt = 0;
                for (int j = 0; j < 4; ++j) { b4[j] = h[lane * 4 + j]; lt += b4[j]; }
                unsigned int sx = lt;
                for (int off = 1; off < 64; off <<= 1) {
                    unsigned int t2 = __shfl_down(sx, off);
                    sx += (lane + off < 64) ? t2 : 0u;
                }
                unsigned int after = sx - lt;
                unsigned int target = (unsigned)KK - cg;
                unsigned int sn2 = after;
                for (int j = 3; j >= 0; --j) {
                    unsigned int s = sn2 + b4[j];
                    if (s >= target && sn2 < target) {
                        unsigned int bin = (unsigned)(lane * 4 + j);
                        s_region = b4[j];
                        s_cntgt = cg + sn2;
                        s_prefix = (shift == 56) ? (u64)bin : ((pref << 8) | (u64)bin);
                    }
                    sn2 = s;
                }
            }
            __syncthreads();
            if (s_cntgt + s_region <= (unsigned)OUT_CAP) break;
        }
        if (shift < 0) shift = 0;
        thr = s_prefix << shift;
        seln = (int)(s_cntgt + s_region);
    }
    (void)seln;

    // write keys >= thr to this slice's private global region
    if (tid == 0) s_sc = 0;
    __syncthreads();
    u64* outslice = cand + (size_t)(b * SLICES + x) * OUT_CAP;
    for (int r0 = 0; r0 < LOCAL_CAP / 1024; ++r0) {
        int i = tid + r0 * 1024;
        u64 k = (i < m) ? keys[i] : 0ULL;
        bool pq = (i < m) && (k >= thr);
        u64 mb = __ballot(pq);
        int pre = __popcll(mb & ((1ULL << lane) - 1ULL));
        int tt = __popcll(mb);
        int base = 0;
        if (lane == 0 && tt > 0) base = atomicAdd(&s_sc, tt);
        base = __shfl(base, 0);
        if (pq && base + pre < OUT_CAP) outslice[base + pre] = k;
    }
    __syncthreads();
    if (tid == 0) {
        int c = s_sc; if (c > OUT_CAP) c = OUT_CAP;
        cnts[b * SLICES + x] = (unsigned)c;
    }
}

// ---- stage 2: merge slices, exact top-500, class-partitioned NMS, outputs ----
__global__ __launch_bounds__(1024) void final_kernel(const float* __restrict__ pboxes,
                                                     const int* __restrict__ plabels,
                                                     const u64* __restrict__ cand,
                                                     const unsigned int* __restrict__ cnts,
                                                     float* __restrict__ out) {
    __shared__ u64 kbuf[M_CAP];         // keys -> later IoU mask rows (500*8 u64)
    __shared__ u64 sel[OUT_CAP];
    __shared__ float sboxes[KK * 4];
    __shared__ float sscore[KK];
    __shared__ int slabel[KK];
    __shared__ int clist[KK];
    __shared__ unsigned int h[256];
    __shared__ int ccnt[21], coff[22], cfill[21];
    __shared__ u64 validw[8];
    __shared__ int kept[KEEPN];
    __shared__ float wred[16];
    __shared__ int soff[SLICES + 1];
    __shared__ u64 s_prefix;
    __shared__ unsigned int s_region, s_cntgt;
    __shared__ int s_sc, s_nk;
    __shared__ float s_maxc;

    const int b = blockIdx.x;
    const int tid = threadIdx.x;
    const int lane = tid & 63;
    const int wv = tid >> 6;

    // concatenate slice key lists
    if (tid == 0) {
        int acc = 0;
        for (int s = 0; s < SLICES; ++s) {
            soff[s] = acc;
            int c = (int)cnts[b * SLICES + s];
            if (c > OUT_CAP) c = OUT_CAP;
            acc += c;
        }
        soff[SLICES] = acc;
    }
    __syncthreads();
    int m = soff[SLICES];
    for (int s = 0; s < SLICES; ++s) {
        int off = soff[s], len = soff[s + 1] - off;
        const u64* src = cand + (size_t)(b * SLICES + s) * OUT_CAP;
        for (int i = tid; i < len; i += 1024) kbuf[off + i] = src[i];
    }
    __syncthreads();

    // ---- phase C: radix-narrow to <= OUT_CAP ----
    u64 thr; int seln;
    if (m <= OUT_CAP) {
        thr = 0ULL; seln = m;
    } else {
        if (tid == 0) { s_prefix = 0ULL; s_cntgt = 0u; }
        __syncthreads();
        int shift = 56;
        for (; shift >= 0; shift -= 8) {
            if (tid < 256) h[tid] = 0u;
            __syncthreads();
            u64 pref = s_prefix;
            unsigned int cg = s_cntgt;
            for (int i = tid; i < m; i += 1024) {
                u64 k = kbuf[i];
                bool match = (shift == 56) || ((k >> (shift + 8)) == pref);
                if (match) atomicAdd(&h[(unsigned int)((k >> shift) & 0xFF)], 1u);
            }
            __syncthreads();
            if (wv == 0) {
                unsigned int b4[4]; unsigned int lt = 0;
                for (int j = 0; j < 4; ++j) { b4[j] = h[lane * 4 + j]; lt += b4[j]; }
                unsigned int sx = lt;
                for (int off = 1; off < 64; off <<= 1) {
                    unsigned int t2 = __shfl_down(sx, off);
                    sx += (lane + off < 64) ? t2 : 0u;
                }
                unsigned int after = sx - lt;
                unsigned int target = (unsigned)KK - cg;
                unsigned int sn2 = after;
                for (int j = 3; j >= 0; --j) {
                    unsigned int s = sn2 + b4[j];
                    if (s >= target && sn2 < target) {
                        unsigned int bin = (unsigned)(lane * 4 + j);
                        s_region = b4[j];
                        s_cntgt = cg + sn2;
                        s_prefix = (shift == 56) ? (u64)bin : ((pref << 8) | (u64)bin);
                    }
                    sn2 = s;
                }
            }
            __syncthreads();
            if (s_cntgt + s_region <= (unsigned)OUT_CAP) break;
        }
        if (shift < 0) shift = 0;
        thr = s_prefix << shift;
        seln = (int)(s_cntgt + s_region);
    }

    // ---- phase D: gather >= thr, readlane-broadcast rank, scatter sorted ----
    if (tid == 0) s_sc = 0;
    __syncthreads();
    for (int r0 = 0; r0 < (M_CAP + 1023) / 1024; ++r0) {
        int i = tid + r0 * 1024;
        u64 k = (i < m) ? kbuf[i] : 0ULL;
        bool pq = (i < m) && (k >= thr);
        u64 mb = __ballot(pq);
        int pre = __popcll(mb & ((1ULL << lane) - 1ULL));
        int tt = __popcll(mb);
        int base = 0;
        if (lane == 0 && tt > 0) base = atomicAdd(&s_sc, tt);
        base = __shfl(base, 0);
        if (pq) sel[base + pre] = k;
    }
    __syncthreads();

    u64 myk = (tid < seln) ? sel[tid] : 0ULL;
    int r = 0;
    if ((tid & ~63) < seln) {
        for (int base = 0; base < seln; base += 64) {
            int i2 = base + lane;
            u64 other = (i2 < seln) ? sel[i2] : 0ULL;
            unsigned int olo = (unsigned int)other, ohi = (unsigned int)(other >> 32);
            int lim = seln - base; if (lim > 64) lim = 64;
            for (int t2 = 0; t2 < lim; ++t2) {
                unsigned int blo = (unsigned int)__builtin_amdgcn_readlane((int)olo, t2);
                unsigned int bhi = (unsigned int)__builtin_amdgcn_readlane((int)ohi, t2);
                u64 o = ((u64)bhi << 32) | (u64)blo;
                r += (o > myk) ? 1 : 0;
            }
        }
    }
    __syncthreads();
    if (tid < seln && r < KK) sel[r] = myk;
    __syncthreads();

    // ---- phase E: extract, NMS, outputs (numerics identical to R4; absmax 0) ----
    float sc = -1.0f;
    if (tid < KK) {
        u64 key = sel[tid];
        unsigned int lo = (unsigned int)key;
        unsigned int hi = (unsigned int)(key >> 32);
        int idx = (int)(~lo);
        unsigned int bits = (hi & 0x80000000u) ? (hi & 0x7FFFFFFFu) : ~hi;
        sc = __uint_as_float(bits);
        sscore[tid] = sc;
        const float4 bx = *(const float4*)(pboxes + (((size_t)b * NN + (size_t)idx) << 2));
        sboxes[tid * 4 + 0] = bx.x; sboxes[tid * 4 + 1] = bx.y;
        sboxes[tid * 4 + 2] = bx.z; sboxes[tid * 4 + 3] = bx.w;
        slabel[tid] = plabels[(size_t)b * NN + idx];
    }
    __syncthreads();

    bool vq = (tid < KK) && (sc > CONF);
    u64 bm = __ballot(vq);
    if (lane == 0 && wv < 8) validw[wv] = bm;
    float lm = vq ? fmaxf(fmaxf(sboxes[tid * 4 + 0], sboxes[tid * 4 + 1]),
                          fmaxf(sboxes[tid * 4 + 2], sboxes[tid * 4 + 3])) : 0.0f;
    for (int off = 32; off > 0; off >>= 1) lm = fmaxf(lm, __shfl_down(lm, off));
    if (lane == 0) wred[wv] = lm;
    __syncthreads();
    if (tid < 64) {
        float x = (tid < 16) ? wred[tid] : 0.0f;
        for (int off = 8; off > 0; off >>= 1) x = fmaxf(x, __shfl_down(x, off));
        if (tid == 0) s_maxc = x;
    }
    if (tid < 21) { ccnt[tid] = 0; cfill[tid] = 0; }
    __syncthreads();
    if (tid < KK) atomicAdd(&ccnt[slabel[tid]], 1);
    __syncthreads();
    if (tid == 0) {
        int acc = 0;
        for (int c = 0; c < 21; ++c) { coff[c] = acc; acc += ccnt[c]; }
        coff[21] = acc;
    }
    __syncthreads();
    if (tid < KK) {
        int c = slabel[tid];
        int pos = atomicAdd(&cfill[c], 1);
        clist[coff[c] + pos] = tid;
    }
    for (int i = tid; i < KK * 8; i += 1024) kbuf[i] = 0ULL;
    __syncthreads();

    float ap1 = s_maxc + 1.0f;
    if (tid < KK) {
        int c = slabel[tid];
        int n = ccnt[c], base0 = coff[c];
        float aoff = (float)c * ap1;
        float a0 = sboxes[tid * 4 + 0] + aoff, a1 = sboxes[tid * 4 + 1] + aoff;
        float a2 = sboxes[tid * 4 + 2] + aoff, a3 = sboxes[tid * 4 + 3] + aoff;
        float areaA = (a2 - a0) * (a3 - a1);
        for (int q = 0; q < n; ++q) {
            int j = clist[base0 + q];
            float b0 = sboxes[j * 4 + 0] + aoff, b1f = sboxes[j * 4 + 1] + aoff;
            float b2f = sboxes[j * 4 + 2] + aoff, b3f = sboxes[j * 4 + 3] + aoff;
            float lt0 = fmaxf(a0, b0), lt1 = fmaxf(a1, b1f);
            float rb0 = fminf(a2, b2f), rb1 = fminf(a3, b3f);
            float ww = fmaxf(rb0 - lt0, 0.0f), hh = fmaxf(rb1 - lt1, 0.0f);
            float inter = ww * hh;
            float areaB = (b2f - b0) * (b3f - b1f);
            float iou = inter / (areaA + areaB - inter);
            if (iou > NMSTHR) kbuf[tid * 8 + (j >> 6)] |= (1ULL << (j & 63));
        }
    }
    __syncthreads();

    if (tid < 64) {
        u64 remv = 0ULL;
        u64 vw_reg = (lane < 8) ? validw[lane] : 0ULL;
        int nk = 0;
        for (int i = 0; i < KK && nk < KEEPN; ++i) {
            int w = i >> 6, bpos = i & 63;
            u64 rw = __shfl(remv, w);
            u64 vv = __shfl(vw_reg, w);
            bool alive = (((vv >> bpos) & 1ULL) != 0ULL) && (((rw >> bpos) & 1ULL) == 0ULL);
            if (alive) {
                if (lane == 0) kept[nk] = i;
                u64 roww = (lane < 8) ? kbuf[i * 8 + lane] : 0ULL;
                remv |= roww;
                nk++;
            }
        }
        if (lane == 0) s_nk = nk;
    }
    __syncthreads();

    if (tid < KEEPN) {
        const int O_BOX = BB * KEEPN;
        const int O_LAB = BB * KEEPN * 5;
        const int O_SCO = BB * KEEPN * 6;
        const int O_VAL = BB * KEEPN * 7;
        bool q = tid < s_nk;
        int i = q ? kept[tid] : 0;
        int g = b * KEEPN + tid;
        out[g]                 = q ? (float)b : -1.0f;
        out[O_BOX + g * 4 + 0] = q ? sboxes[i * 4 + 0] : 0.0f;
        out[O_BOX + g * 4 + 1] = q ? sboxes[i * 4 + 1] : 0.0f;
        out[O_BOX + g * 4 + 2] = q ? sboxes[i * 4 + 2] : 0.0f;
        out[O_BOX + g * 4 + 3] = q ? sboxes[i * 4 + 3] : 0.0f;
        out[O_LAB + g]         = q ? (float)slabel[i] : -1.0f;
        out[O_SCO + g]         = q ? sscore[i] : 0.0f;
        out[O_VAL + g]         = q ? 1.0f : 0.0f;
    }
}

extern "C" void kernel_launch(void* const* d_in, const int* in_sizes, int n_in,
                              void* d_out, int out_size, void* d_ws, size_t ws_size,
                              hipStream_t stream) {
    const float* pscores = (const float*)d_in[0];
    const float* pboxes  = (const float*)d_in[1];
    const int*   plabels = (const int*)d_in[2];
    float* out = (float*)d_out;

    uint8_t* ws = (uint8_t*)d_ws;
    u64*          cand = (u64*)(ws + 0);
    unsigned int* cnts = (unsigned int*)(ws + 1179648);

    select_kernel<<<dim3(SLICES, BB), 1024, 0, stream>>>((const float4*)pscores, cand, cnts);
    final_kernel<<<BB, 1024, 0, stream>>>(pboxes, plabels, cand, cnts, out);
}